// Round 6
// baseline (191.586 us; speedup 1.0000x reference)
//
#include <hip/hip_runtime.h>
#include <hip/hip_bf16.h>
#include <math.h>

#define Bsz 2
#define Tseq 2048
#define Cdim 1024
#define Hn 16
#define HDim 64
#define Mrows 4096
#define N3 3072
#define QSCALE 0.1803368801111137f   /* 0.125 * log2(e) baked into Q */

typedef __bf16 bf16_t;
typedef __bf16 bf16x4 __attribute__((ext_vector_type(4)));
typedef __bf16 bf16x8 __attribute__((ext_vector_type(8)));
typedef float floatx4 __attribute__((ext_vector_type(4)));

__device__ __forceinline__ void async16(const void* g, void* l) {
    __builtin_amdgcn_global_load_lds(
        (const __attribute__((address_space(1))) void*)g,
        (__attribute__((address_space(3))) void*)l, 16, 0, 0);
}

// ---------------------------------------------------------------------------
// prep: fused fp32->bf16 convert of x + transpose-convert of w_attn, w_proj.
// ---------------------------------------------------------------------------
__global__ __launch_bounds__(256) void prep_kernel(
    const float* __restrict__ x, const float* __restrict__ w_attn,
    const float* __restrict__ w_proj, bf16_t* __restrict__ xb,
    bf16_t* __restrict__ waT, bf16_t* __restrict__ wpT)
{
    __shared__ float Ts[32][33];
    const int bid = blockIdx.x;
    if (bid < 2048) {
        size_t g = (size_t)bid * 256 + threadIdx.x;
        float4 a = *(const float4*)(x + g * 8);
        float4 b = *(const float4*)(x + g * 8 + 4);
        bf16x8 o;
        o[0] = (bf16_t)a.x; o[1] = (bf16_t)a.y; o[2] = (bf16_t)a.z; o[3] = (bf16_t)a.w;
        o[4] = (bf16_t)b.x; o[5] = (bf16_t)b.y; o[6] = (bf16_t)b.z; o[7] = (bf16_t)b.w;
        *(bf16x8*)(xb + g * 8) = o;
        return;
    }
    const float* in; bf16_t* out; int R, C, bx, by;
    if (bid < 5120) {
        int t = bid - 2048; in = w_attn; out = waT; R = Cdim; C = N3;
        bx = t % 96; by = t / 96;
    } else {
        int t = bid - 5120; in = w_proj; out = wpT; R = Cdim; C = Cdim;
        bx = t & 31; by = t >> 5;
    }
    int c0 = bx << 5, r0 = by << 5;
    int lr = threadIdx.x >> 3, lc = (threadIdx.x & 7) << 2;
    float4 v = *(const float4*)(in + (size_t)(r0 + lr) * C + c0 + lc);
    Ts[lr][lc] = v.x; Ts[lr][lc + 1] = v.y; Ts[lr][lc + 2] = v.z; Ts[lr][lc + 3] = v.w;
    __syncthreads();
    bf16x4 o;
    o[0] = (bf16_t)Ts[lc + 0][lr]; o[1] = (bf16_t)Ts[lc + 1][lr];
    o[2] = (bf16_t)Ts[lc + 2][lr]; o[3] = (bf16_t)Ts[lc + 3][lr];
    *(bf16x4*)(out + (size_t)(c0 + lr) * R + r0 + lc) = o;
}

// ---------------------------------------------------------------------------
// QKV GEMM, r12: 8-phase 256^2 schedule (T3+T4+T5). The m97-style 128^2 loop
// is structurally capped at ~45us: every __syncthreads() drains vmcnt(0)
// (4 rounds of evidence: dbuf x2, BK=64, XCD remap all null/negative).
// This kernel replaces it: raw s_barrier + counted vmcnt — loads stay in
// flight across barriers.
//   tile 256x256, BK=64, 512 thr = 8 waves (2M x 4N), wave tile 128x64.
//   LDS 128KB: {A,B} x {buf0,buf1} x {klo,khi} halves of 256rows x 32cols.
//   Stage granularity = one k-half (1024 chunks, 2 async16/thread).
//   8 phases/iter (2 K-tiles): ph = (buf, k-slice S, row-half RH); per phase:
//   8 ds_read_b128 + 1 half staged + bar + MFMA x16 (setprio) + bar.
//   Stage map: ph1,2->khi(O) ph3,4->klo(E+2) ph5,6->khi(E+2) ph7,8->klo(O+2)
//   (each slot freed by barrier >=1 phase earlier — WAR safe).
//   vmcnt(4) BEFORE ph1,3,5,7 reads: drains the 2-oldest halves, giving every
//   read a >=1-full-barrier margin after ALL waves drained it (cross-wave
//   RAW safe; per-wave vmcnt + barrier-ordering argument).
//   Prologue stages 6 halves + vmcnt(8); last iter peeled w/ vmcnt(4/4/0).
//   Swizzle: slot = chunk ^ ((row>>1)&3) both-sides -> 2-way (free) reads.
// Epilogue unchanged: bias + rotary(q,k) + QSCALE; v -> (BH,HD,T) sigma-perm.
// ---------------------------------------------------------------------------
#define VMW(N) asm volatile("s_waitcnt vmcnt(" #N ")" ::: "memory")

#define STAGE(HALF, SRC, KOFF) do {                                          \
    _Pragma("unroll") for (int _it = 0; _it < 2; ++_it) {                    \
        int _ci = (_it << 9) + tid;                                          \
        int _r = _ci >> 2, _sl = _ci & 3;                                    \
        int _cg = _sl ^ ((_r >> 1) & 3);                                     \
        async16((SRC) + (size_t)_r * Cdim + (KOFF) + _cg * 8,                \
                (HALF) + ((_it << 9) + (w << 6)) * 8);                       \
    } } while (0)

#define PHASE(AARR, BARR, S, RH, ...) do {                                   \
    bf16x8 _af[4], _bf[4];                                                   \
    _Pragma("unroll") for (int _f = 0; _f < 4; ++_f) {                       \
        int _ra = (wy << 7) + ((RH) << 6) + (_f << 4) + lm;                  \
        _af[_f] = *(const bf16x8*)&AARR[S][(_ra * 4 + (quad ^ ((_ra >> 1) & 3))) * 8]; \
        int _rb = (wx << 6) + (_f << 4) + lm;                                \
        _bf[_f] = *(const bf16x8*)&BARR[S][(_rb * 4 + (quad ^ ((_rb >> 1) & 3))) * 8]; \
    }                                                                        \
    __VA_ARGS__;                                                             \
    __builtin_amdgcn_s_barrier();                                            \
    __builtin_amdgcn_s_setprio(1);                                           \
    _Pragma("unroll") for (int _f = 0; _f < 4; ++_f)                         \
        _Pragma("unroll") for (int _j = 0; _j < 4; ++_j)                     \
            acc[((RH) << 2) + _f][_j] = __builtin_amdgcn_mfma_f32_16x16x32_bf16( \
                _af[_f], _bf[_j], acc[((RH) << 2) + _f][_j], 0, 0, 0);       \
    __builtin_amdgcn_s_setprio(0);                                           \
    __builtin_amdgcn_s_barrier();                                            \
} while (0)

__global__ __launch_bounds__(512) void gemm_qkv(
    const bf16_t* __restrict__ xb, const bf16_t* __restrict__ waT,
    const float* __restrict__ bias, const float* __restrict__ cosb,
    const float* __restrict__ sinb,
    bf16_t* __restrict__ qb, bf16_t* __restrict__ kb, bf16_t* __restrict__ vt)
{
    __shared__ bf16_t A0[2][8192];   // buf0 A: [khalf][256rows x 4chunks x 8]
    __shared__ bf16_t B0[2][8192];
    __shared__ bf16_t A1[2][8192];   // buf1
    __shared__ bf16_t B1[2][8192];

    const int tid = threadIdx.x;
    const int lane = tid & 63, w = tid >> 6;
    const int lm = lane & 15, quad = lane >> 4;
    const int wy = w >> 2, wx = w & 3;
    // XCD-chunked remap: 192 blocks = 8 xcd x 24; each XCD a 4m x 6n rect.
    const int bid = blockIdx.x;
    const int xcd = bid & 7, idx = bid >> 3;
    const int gn = (xcd & 1) * 6 + idx % 6;
    const int gm = (xcd >> 1) * 4 + idx / 6;
    const int m0 = gm << 8, n0 = gn << 8;

    const floatx4 fz = {0.f, 0.f, 0.f, 0.f};
    floatx4 acc[8][4];
    #pragma unroll
    for (int i = 0; i < 8; i++)
        #pragma unroll
        for (int j = 0; j < 4; j++) acc[i][j] = fz;

    const bf16_t* Ag = xb + (size_t)m0 * Cdim;
    const bf16_t* Bg = waT + (size_t)n0 * Cdim;

    // prologue: tiles 0 (full) + klo of tile 1; drain klo(0); align.
    STAGE(A0[0], Ag, 0);  STAGE(B0[0], Bg, 0);
    STAGE(A0[1], Ag, 32); STAGE(B0[1], Bg, 32);
    STAGE(A1[0], Ag, 64); STAGE(B1[0], Bg, 64);
    VMW(8);
    __builtin_amdgcn_s_barrier();

    for (int t2 = 0; t2 < 7; ++t2) {          // iterations 0..6: tiles 2t2, 2t2+1
        const int kE = t2 << 7;
        VMW(4); PHASE(A0, B0, 0, 0, STAGE(A1[1], Ag, kE + 96));
                PHASE(A0, B0, 0, 1, STAGE(B1[1], Bg, kE + 96));
        VMW(4); PHASE(A0, B0, 1, 0, STAGE(A0[0], Ag, kE + 128));
                PHASE(A0, B0, 1, 1, STAGE(B0[0], Bg, kE + 128));
        VMW(4); PHASE(A1, B1, 0, 0, STAGE(A0[1], Ag, kE + 160));
                PHASE(A1, B1, 0, 1, STAGE(B0[1], Bg, kE + 160));
        VMW(4); PHASE(A1, B1, 1, 0, STAGE(A1[0], Ag, kE + 192));
                PHASE(A1, B1, 1, 1, STAGE(B1[0], Bg, kE + 192));
    }
    // peeled final iteration: tiles 14,15 (only khi(15) left to stage)
    VMW(4); PHASE(A0, B0, 0, 0, STAGE(A1[1], Ag, 992));
            PHASE(A0, B0, 0, 1, STAGE(B1[1], Bg, 992));
    VMW(4); PHASE(A0, B0, 1, 0, ((void)0));
            PHASE(A0, B0, 1, 1, ((void)0));
    VMW(0); PHASE(A1, B1, 0, 0, ((void)0));
            PHASE(A1, B1, 0, 1, ((void)0));
            PHASE(A1, B1, 1, 0, ((void)0));
            PHASE(A1, B1, 1, 1, ((void)0));

    // epilogue: C/D layout col=lane&15, row=quad*4+reg
    const int sec = n0 >> 10;                 // block-uniform: 0=q 1=k 2=v
    const int mb = m0 + (wy << 7);
    const int nb = n0 + (wx << 6);
    #pragma unroll
    for (int i = 0; i < 8; i++) {
        int mrow0 = mb + (i << 4) + (quad << 2);
        int b = mrow0 >> 11, t0 = mrow0 & 2047;
        #pragma unroll
        for (int j = 0; j < 4; j++) {
            int n = nb + (j << 4) + lm;
            float bi = bias[n];
            int rel = n & 1023;
            int h = rel >> 6, hd = rel & 63;
            if (sec == 2) {
                int tp = (t0 & ~31) | (((t0 >> 2) & 3) << 3) | (((t0 >> 4) & 1) << 2);
                bf16x4 pk;
                #pragma unroll
                for (int r = 0; r < 4; r++) pk[r] = (bf16_t)(acc[i][j][r] + bi);
                *(bf16x4*)&vt[((size_t)(b * Hn + h) * HDim + hd) * Tseq + tp] = pk;
            } else {
                bf16_t* dst = (sec == 0) ? qb : kb;
                const int ih = hd >> 1;
                const bool ev = !(hd & 1);
                #pragma unroll
                for (int r = 0; r < 4; r++) {
                    int t = t0 + r;
                    float v = acc[i][j][r] + bi;
                    float x = __shfl_xor(v, 1);        // rotary pair partner
                    float c = cosb[t * 32 + ih], s = sinb[t * 32 + ih];
                    float rv = ev ? (v * c - x * s) : (x * s + v * c);
                    if (sec == 0) rv *= QSCALE;
                    dst[((size_t)(b * Hn + h) * Tseq + t) * HDim + hd] = (bf16_t)rv;
                }
            }
        }
    }
}

// ---------------------------------------------------------------------------
// Flash attention (r7 structure, measured win; no setprio — m190 regime).
// ONE 64-row q-tile per block, 1024 blocks x 256 threads, 4 blocks/CU.
// NO-MAX softmax: P=exp2(s) directly (scores bounded), l=sum(P), normalize
// in epilogue. PV = V^T P^T with key permutation sigma baked into vt.
// ---------------------------------------------------------------------------
__global__ __launch_bounds__(256) void attn_mfma(
    const bf16_t* __restrict__ qb, const bf16_t* __restrict__ kb,
    const bf16_t* __restrict__ vt, bf16_t* __restrict__ yb)
{
    __shared__ bf16_t Ks[2][64 * 64];       // 16 KB dbuf
    __shared__ bf16_t VTs[2][64 * 64];      // 16 KB dbuf

    const int bid = blockIdx.x;
    const int jt = 31 - (bid >> 5);          // long blocks dispatch first
    const int bh = bid & 31;
    const int b = bh >> 4, h = bh & 15;
    const int tid = threadIdx.x;
    const int w4 = tid >> 6, lane = tid & 63, lm = lane & 15, quad = lane >> 4;
    const int nk = jt + 1;                   // kt = 0 .. jt (causal)

    // stage K/V tile 0
    {
        const bf16_t* Kg = kb + (size_t)bh * Tseq * HDim;
        const bf16_t* Vg = vt + (size_t)bh * HDim * Tseq;
        #pragma unroll
        for (int it = 0; it < 2; ++it) {
            int ci = (it << 8) + tid;
            int row = ci >> 3, cq = (ci & 7) ^ (row & 7);
            async16(Kg + row * HDim + cq * 8, &Ks[0][((it << 8) + (w4 << 6)) * 8]);
            async16(Vg + (size_t)row * Tseq + cq * 8, &VTs[0][((it << 8) + (w4 << 6)) * 8]);
        }
    }

    // loop-invariant Q fragments straight from global (B-operand: n=lm, k)
    const int qq = (jt << 6) + (w4 << 4) + lm;   // this lane's q row
    bf16x8 qf[2];
    {
        const bf16_t* Qg = qb + ((size_t)bh * Tseq + qq) * HDim;
        #pragma unroll
        for (int ks = 0; ks < 2; ++ks)
            qf[ks] = *(const bf16x8*)(Qg + (ks << 5) + (quad << 3));
    }
    __syncthreads();

    const floatx4 fz = {0.f, 0.f, 0.f, 0.f};
    floatx4 o_[4];                           // O^T: [d-subtile]
    #pragma unroll
    for (int f = 0; f < 4; ++f) o_[f] = fz;
    float l_ = 0.f;

    for (int kt = 0; kt < nk; ++kt) {
        const int cb = kt & 1;
        if (kt + 1 < nk) {                    // prefetch next K/V tile
            const int nb2 = cb ^ 1;
            const bf16_t* Kg = kb + ((size_t)bh * Tseq + ((kt + 1) << 6)) * HDim;
            const bf16_t* Vg = vt + (size_t)bh * HDim * Tseq + ((kt + 1) << 6);
            #pragma unroll
            for (int it = 0; it < 2; ++it) {
                int ci = (it << 8) + tid;
                int row = ci >> 3, cq = (ci & 7) ^ (row & 7);
                async16(Kg + row * HDim + cq * 8, &Ks[nb2][((it << 8) + (w4 << 6)) * 8]);
                async16(Vg + (size_t)row * Tseq + cq * 8, &VTs[nb2][((it << 8) + (w4 << 6)) * 8]);
            }
        }

        // S^T = K Q^T (rows = keys, cols = q)
        floatx4 st[4];
        #pragma unroll
        for (int sub = 0; sub < 4; ++sub) st[sub] = fz;
        #pragma unroll
        for (int ks = 0; ks < 2; ++ks) {
            bf16x8 kf[4];
            #pragma unroll
            for (int sub = 0; sub < 4; ++sub) {
                int krow = (sub << 4) + lm;
                int kc = ((ks << 2) + quad) ^ (krow & 7);
                kf[sub] = *(const bf16x8*)&Ks[cb][krow * 64 + kc * 8];
            }
            #pragma unroll
            for (int sub = 0; sub < 4; ++sub)
                st[sub] = __builtin_amdgcn_mfma_f32_16x16x32_bf16(
                    kf[sub], qf[ks], st[sub], 0, 0, 0);
        }

        // no-max softmax: P = exp2(s) (bf16), l += sum(P)
        const bool dm = (kt == jt);           // diagonal tile -> causal mask
        bf16x8 pf[2];                         // B-operand P frags (key halves)
        float rs = 0.f;
        #pragma unroll
        for (int cc = 0; cc < 2; ++cc)
            #pragma unroll
            for (int jj = 0; jj < 8; ++jj) {
                int sub = (cc << 1) + (jj >> 2), r = jj & 3;
                float val = st[sub][r];
                if (dm) {
                    int key = (kt << 6) + (sub << 4) + (quad << 2) + r;
                    if (key > qq) val = -3e38f;
                }
                float p = exp2f(val);
                rs += p;
                pf[cc][jj] = (bf16_t)p;
            }
        rs += __shfl_xor(rs, 16);
        rs += __shfl_xor(rs, 32);
        l_ += rs;

        // O^T += V^T P^T (sigma key-permutation baked into vt layout)
        #pragma unroll
        for (int cc = 0; cc < 2; ++cc) {
            bf16x8 vf[4];
            #pragma unroll
            for (int f = 0; f < 4; ++f) {
                int vrow = (f << 4) + lm;
                int vc = ((cc << 2) + quad) ^ (vrow & 7);
                vf[f] = *(const bf16x8*)&VTs[cb][vrow * 64 + vc * 8];
            }
            #pragma unroll
            for (int f = 0; f < 4; ++f)
                o_[f] = __builtin_amdgcn_mfma_f32_16x16x32_bf16(
                    vf[f], pf[cc], o_[f], 0, 0, 0);
        }
        __syncthreads();
    }

    // epilogue: O^T lane holds q=qq, d = f*16+quad*4+r
    {
        float inv = 1.f / l_;
        size_t base = ((size_t)(b * Tseq) + qq) * Cdim + (h << 6) + (quad << 2);
        #pragma unroll
        for (int f = 0; f < 4; ++f) {
            bf16x4 ov;
            #pragma unroll
            for (int r = 0; r < 4; ++r) ov[r] = (bf16_t)(o_[f][r] * inv);
            *(bf16x4*)&yb[base + (f << 4)] = ov;
        }
    }
}

// ---------------------------------------------------------------------------
// Proj GEMM: (4096x1024) @ (1024x1024) + bias -> fp32 out.
// r5 form: r1 body + XCD-chunked remap.
// ---------------------------------------------------------------------------
__global__ __launch_bounds__(256) void gemm_proj(
    const bf16_t* __restrict__ yb, const bf16_t* __restrict__ wpT,
    const float* __restrict__ bias, float* __restrict__ out)
{
    __shared__ bf16_t As[128 * 32];
    __shared__ bf16_t Bs[128 * 32];
    const int tid = threadIdx.x;
    const int lane = tid & 63, w = tid >> 6;
    const int lm = lane & 15, quad = lane >> 4;
    const int wy = w >> 1, wx = w & 1;
    const int bid = blockIdx.x;
    const int xcd = bid & 7, i5 = bid >> 3;
    const int gn = i5 & 7;
    const int gm = (xcd << 2) + (i5 >> 3);
    const int m0 = gm << 7, n0 = gn << 7;

    const floatx4 fz = {0.f, 0.f, 0.f, 0.f};
    floatx4 acc[4][4];
    #pragma unroll
    for (int i = 0; i < 4; i++)
        #pragma unroll
        for (int j = 0; j < 4; j++) acc[i][j] = fz;

    const bf16_t* Ag = yb + (size_t)m0 * Cdim;
    const bf16_t* Bg = wpT + (size_t)n0 * Cdim;

    for (int k0 = 0; k0 < Cdim; k0 += 32) {
        #pragma unroll
        for (int it = 0; it < 2; ++it) {
            int ci = (w << 7) + (it << 6) + lane;
            int row = ci >> 2, cq = (ci & 3) ^ (row & 3);
            async16(Ag + (size_t)row * Cdim + k0 + cq * 8, As + ((w << 7) + (it << 6)) * 8);
            async16(Bg + (size_t)row * Cdim + k0 + cq * 8, Bs + ((w << 7) + (it << 6)) * 8);
        }
        __syncthreads();
        bf16x8 af[4], bfr[4];
        #pragma unroll
        for (int i = 0; i < 4; i++) {
            int row = (wy << 6) + (i << 4) + lm;
            int cq = quad ^ (lm & 3);
            af[i] = *(const bf16x8*)&As[row * 32 + cq * 8];
        }
        #pragma unroll
        for (int j = 0; j < 4; j++) {
            int row = (wx << 6) + (j << 4) + lm;
            int cq = quad ^ (lm & 3);
            bfr[j] = *(const bf16x8*)&Bs[row * 32 + cq * 8];
        }
        #pragma unroll
        for (int i = 0; i < 4; i++)
            #pragma unroll
            for (int j = 0; j < 4; j++)
                acc[i][j] = __builtin_amdgcn_mfma_f32_16x16x32_bf16(af[i], bfr[j], acc[i][j], 0, 0, 0);
        __syncthreads();
    }

    const int mb = m0 + (wy << 6);
    const int nb = n0 + (wx << 6);
    #pragma unroll
    for (int i = 0; i < 4; i++) {
        int mrow0 = mb + (i << 4) + (quad << 2);
        #pragma unroll
        for (int j = 0; j < 4; j++) {
            int n = nb + (j << 4) + lm;
            float bi = bias[n];
            #pragma unroll
            for (int r = 0; r < 4; r++)
                out[(size_t)(mrow0 + r) * Cdim + n] = acc[i][j][r] + bi;
        }
    }
}

extern "C" void kernel_launch(void* const* d_in, const int* in_sizes, int n_in,
                              void* d_out, int out_size, void* d_ws, size_t ws_size,
                              hipStream_t stream) {
    const float* x      = (const float*)d_in[0];
    const float* cosb   = (const float*)d_in[1];
    const float* sinb   = (const float*)d_in[2];
    const float* w_attn = (const float*)d_in[3];
    const float* b_attn = (const float*)d_in[4];
    const float* w_proj = (const float*)d_in[5];
    const float* b_proj = (const float*)d_in[6];

    char* ws = (char*)d_ws;
    bf16_t* xb  = (bf16_t*)(ws);                       //  8 MB: x bf16 (M,K)
    bf16_t* waT = (bf16_t*)(ws + (size_t)(8 << 20));   //  6 MB: w_attn^T (N,K)
    bf16_t* wpT = (bf16_t*)(ws + (size_t)(14 << 20));  //  2 MB: w_proj^T (N,K)
    bf16_t* qb  = (bf16_t*)(ws + (size_t)(16 << 20));  //  8 MB: q bf16 (BH,T,HD), pre-scaled
    bf16_t* kb  = (bf16_t*)(ws + (size_t)(24 << 20));  //  8 MB: k bf16 (BH,T,HD)
    bf16_t* vtb = (bf16_t*)(ws + (size_t)(32 << 20));  //  8 MB: v^T bf16 (BH,HD,T), key-permuted
    bf16_t* yb  = (bf16_t*)(ws + (size_t)(40 << 20));  //  8 MB: attn out (M,C)

    prep_kernel<<<6144, 256, 0, stream>>>(x, w_attn, w_proj, xb, waT, wpT);
    gemm_qkv<<<192, 512, 0, stream>>>(xb, waT, b_attn, cosb, sinb, qb, kb, vtb);
    attn_mfma<<<1024, 256, 0, stream>>>(qb, kb, vtb, yb);
    gemm_proj<<<256, 256, 0, stream>>>(yb, wpT, b_proj, (float*)d_out);
}

// Round 7
// 185.094 us; speedup vs baseline: 1.0351x; 1.0351x over previous
//
#include <hip/hip_runtime.h>
#include <hip/hip_bf16.h>
#include <math.h>

#define Bsz 2
#define Tseq 2048
#define Cdim 1024
#define Hn 16
#define HDim 64
#define Mrows 4096
#define N3 3072
#define QSCALE 0.1803368801111137f   /* 0.125 * log2(e) baked into Q */

typedef __bf16 bf16_t;
typedef __bf16 bf16x4 __attribute__((ext_vector_type(4)));
typedef __bf16 bf16x8 __attribute__((ext_vector_type(8)));
typedef float floatx4 __attribute__((ext_vector_type(4)));

__device__ __forceinline__ void async16(const void* g, void* l) {
    __builtin_amdgcn_global_load_lds(
        (const __attribute__((address_space(1))) void*)g,
        (__attribute__((address_space(3))) void*)l, 16, 0, 0);
}

// ---------------------------------------------------------------------------
// prep: fused fp32->bf16 convert of x + transpose-convert of w_attn, w_proj.
// blocks 0..2047: convert; 2048..5119: w_attn^T; 5120..6143: w_proj^T.
// ---------------------------------------------------------------------------
__global__ __launch_bounds__(256) void prep_kernel(
    const float* __restrict__ x, const float* __restrict__ w_attn,
    const float* __restrict__ w_proj, bf16_t* __restrict__ xb,
    bf16_t* __restrict__ waT, bf16_t* __restrict__ wpT)
{
    __shared__ float Ts[32][33];
    const int bid = blockIdx.x;
    if (bid < 2048) {
        size_t g = (size_t)bid * 256 + threadIdx.x;
        float4 a = *(const float4*)(x + g * 8);
        float4 b = *(const float4*)(x + g * 8 + 4);
        bf16x8 o;
        o[0] = (bf16_t)a.x; o[1] = (bf16_t)a.y; o[2] = (bf16_t)a.z; o[3] = (bf16_t)a.w;
        o[4] = (bf16_t)b.x; o[5] = (bf16_t)b.y; o[6] = (bf16_t)b.z; o[7] = (bf16_t)b.w;
        *(bf16x8*)(xb + g * 8) = o;
        return;
    }
    const float* in; bf16_t* out; int R, C, bx, by;
    if (bid < 5120) {
        int t = bid - 2048; in = w_attn; out = waT; R = Cdim; C = N3;
        bx = t % 96; by = t / 96;
    } else {
        int t = bid - 5120; in = w_proj; out = wpT; R = Cdim; C = Cdim;
        bx = t & 31; by = t >> 5;
    }
    int c0 = bx << 5, r0 = by << 5;
    int lr = threadIdx.x >> 3, lc = (threadIdx.x & 7) << 2;
    float4 v = *(const float4*)(in + (size_t)(r0 + lr) * C + c0 + lc);
    Ts[lr][lc] = v.x; Ts[lr][lc + 1] = v.y; Ts[lr][lc + 2] = v.z; Ts[lr][lc + 3] = v.w;
    __syncthreads();
    bf16x4 o;
    o[0] = (bf16_t)Ts[lc + 0][lr]; o[1] = (bf16_t)Ts[lc + 1][lr];
    o[2] = (bf16_t)Ts[lc + 2][lr]; o[3] = (bf16_t)Ts[lc + 3][lr];
    *(bf16x4*)(out + (size_t)(c0 + lr) * R + r0 + lc) = o;
}

// ---------------------------------------------------------------------------
// QKV GEMM, r13 = EXACT r5 body (best measured config: qkv 45.1us, total
// 185.06). m97 structure + XCD-chunked remap. Five attempts to beat 45
// (dbuf x2, BK=64, 8-phase 256^2) all regressed — structure ceiling accepted;
// FETCH halved by the remap (38->21.6MB) proving L2 locality works, but the
// kernel is drain-latency-bound, not fetch-bound.
// Epilogue: fused bias + rotary(q,k) + Q pre-scale; v -> (BH,HD,T)
// key-permuted (sigma) so attn's PV B-operand comes straight from P regs.
// ---------------------------------------------------------------------------
__global__ __launch_bounds__(256) void gemm_qkv(
    const bf16_t* __restrict__ xb, const bf16_t* __restrict__ waT,
    const float* __restrict__ bias, const float* __restrict__ cosb,
    const float* __restrict__ sinb,
    bf16_t* __restrict__ qb, bf16_t* __restrict__ kb, bf16_t* __restrict__ vt)
{
    __shared__ bf16_t As[128 * 32];
    __shared__ bf16_t Bs[128 * 32];
    const int tid = threadIdx.x;
    const int lane = tid & 63, w = tid >> 6;
    const int lm = lane & 15, quad = lane >> 4;
    const int wy = w >> 1, wx = w & 1;
    // XCD-chunked remap: x = XCD (bid&7), i = within-XCD index (0..95).
    const int bid = blockIdx.x;
    const int xcd = bid & 7, i5 = bid >> 3;
    const int gn = ((xcd & 1) * 12) + (i5 % 12);
    const int gm = ((xcd >> 1) * 8) + (i5 / 12);
    const int m0 = gm << 7, n0 = gn << 7;

    const floatx4 fz = {0.f, 0.f, 0.f, 0.f};
    floatx4 acc[4][4];
    #pragma unroll
    for (int i = 0; i < 4; i++)
        #pragma unroll
        for (int j = 0; j < 4; j++) acc[i][j] = fz;

    const bf16_t* Ag = xb + (size_t)m0 * Cdim;
    const bf16_t* Bg = waT + (size_t)n0 * Cdim;

    for (int k0 = 0; k0 < Cdim; k0 += 32) {
        #pragma unroll
        for (int it = 0; it < 2; ++it) {
            int ci = (w << 7) + (it << 6) + lane;
            int row = ci >> 2, cq = (ci & 3) ^ (row & 3);
            async16(Ag + (size_t)row * Cdim + k0 + cq * 8, As + ((w << 7) + (it << 6)) * 8);
            async16(Bg + (size_t)row * Cdim + k0 + cq * 8, Bs + ((w << 7) + (it << 6)) * 8);
        }
        __syncthreads();
        bf16x8 af[4], bfr[4];
        #pragma unroll
        for (int i = 0; i < 4; i++) {
            int row = (wy << 6) + (i << 4) + lm;
            int cq = quad ^ (lm & 3);
            af[i] = *(const bf16x8*)&As[row * 32 + cq * 8];
        }
        #pragma unroll
        for (int j = 0; j < 4; j++) {
            int row = (wx << 6) + (j << 4) + lm;
            int cq = quad ^ (lm & 3);
            bfr[j] = *(const bf16x8*)&Bs[row * 32 + cq * 8];
        }
        #pragma unroll
        for (int i = 0; i < 4; i++)
            #pragma unroll
            for (int j = 0; j < 4; j++)
                acc[i][j] = __builtin_amdgcn_mfma_f32_16x16x32_bf16(af[i], bfr[j], acc[i][j], 0, 0, 0);
        __syncthreads();
    }

    // epilogue: C/D layout col=lane&15, row=quad*4+reg
    const int sec = n0 >> 10;                 // block-uniform: 0=q 1=k 2=v
    const int mb = m0 + (wy << 6);
    const int nb = n0 + (wx << 6);
    #pragma unroll
    for (int i = 0; i < 4; i++) {
        int mrow0 = mb + (i << 4) + (quad << 2);
        int b = mrow0 >> 11, t0 = mrow0 & 2047;
        #pragma unroll
        for (int j = 0; j < 4; j++) {
            int n = nb + (j << 4) + lm;
            float bi = bias[n];
            int rel = n & 1023;
            int h = rel >> 6, hd = rel & 63;
            if (sec == 2) {
                int tp = (t0 & ~31) | (((t0 >> 2) & 3) << 3) | (((t0 >> 4) & 1) << 2);
                bf16x4 pk;
                #pragma unroll
                for (int r = 0; r < 4; r++) pk[r] = (bf16_t)(acc[i][j][r] + bi);
                *(bf16x4*)&vt[((size_t)(b * Hn + h) * HDim + hd) * Tseq + tp] = pk;
            } else {
                bf16_t* dst = (sec == 0) ? qb : kb;
                const int ih = hd >> 1;
                const bool ev = !(hd & 1);
                #pragma unroll
                for (int r = 0; r < 4; r++) {
                    int t = t0 + r;
                    float v = acc[i][j][r] + bi;
                    float x = __shfl_xor(v, 1);        // rotary pair partner
                    float c = cosb[t * 32 + ih], s = sinb[t * 32 + ih];
                    float rv = ev ? (v * c - x * s) : (x * s + v * c);
                    if (sec == 0) rv *= QSCALE;
                    dst[((size_t)(b * Hn + h) * Tseq + t) * HDim + hd] = (bf16_t)rv;
                }
            }
        }
    }
}

// ---------------------------------------------------------------------------
// Flash attention (r7 structure, measured win; no setprio — m190 regime).
// ONE 64-row q-tile per block, 1024 blocks x 256 threads, 4 blocks/CU.
// NO-MAX softmax: P=exp2(s) directly (scores bounded), l=sum(P), normalize
// in epilogue. PV = V^T P^T with key permutation sigma baked into vt.
// ---------------------------------------------------------------------------
__global__ __launch_bounds__(256) void attn_mfma(
    const bf16_t* __restrict__ qb, const bf16_t* __restrict__ kb,
    const bf16_t* __restrict__ vt, bf16_t* __restrict__ yb)
{
    __shared__ bf16_t Ks[2][64 * 64];       // 16 KB dbuf
    __shared__ bf16_t VTs[2][64 * 64];      // 16 KB dbuf

    const int bid = blockIdx.x;
    const int jt = 31 - (bid >> 5);          // long blocks dispatch first
    const int bh = bid & 31;
    const int b = bh >> 4, h = bh & 15;
    const int tid = threadIdx.x;
    const int w4 = tid >> 6, lane = tid & 63, lm = lane & 15, quad = lane >> 4;
    const int nk = jt + 1;                   // kt = 0 .. jt (causal)

    // stage K/V tile 0
    {
        const bf16_t* Kg = kb + (size_t)bh * Tseq * HDim;
        const bf16_t* Vg = vt + (size_t)bh * HDim * Tseq;
        #pragma unroll
        for (int it = 0; it < 2; ++it) {
            int ci = (it << 8) + tid;
            int row = ci >> 3, cq = (ci & 7) ^ (row & 7);
            async16(Kg + row * HDim + cq * 8, &Ks[0][((it << 8) + (w4 << 6)) * 8]);
            async16(Vg + (size_t)row * Tseq + cq * 8, &VTs[0][((it << 8) + (w4 << 6)) * 8]);
        }
    }

    // loop-invariant Q fragments straight from global (B-operand: n=lm, k)
    const int qq = (jt << 6) + (w4 << 4) + lm;   // this lane's q row
    bf16x8 qf[2];
    {
        const bf16_t* Qg = qb + ((size_t)bh * Tseq + qq) * HDim;
        #pragma unroll
        for (int ks = 0; ks < 2; ++ks)
            qf[ks] = *(const bf16x8*)(Qg + (ks << 5) + (quad << 3));
    }
    __syncthreads();

    const floatx4 fz = {0.f, 0.f, 0.f, 0.f};
    floatx4 o_[4];                           // O^T: [d-subtile]
    #pragma unroll
    for (int f = 0; f < 4; ++f) o_[f] = fz;
    float l_ = 0.f;

    for (int kt = 0; kt < nk; ++kt) {
        const int cb = kt & 1;
        if (kt + 1 < nk) {                    // prefetch next K/V tile
            const int nb2 = cb ^ 1;
            const bf16_t* Kg = kb + ((size_t)bh * Tseq + ((kt + 1) << 6)) * HDim;
            const bf16_t* Vg = vt + (size_t)bh * HDim * Tseq + ((kt + 1) << 6);
            #pragma unroll
            for (int it = 0; it < 2; ++it) {
                int ci = (it << 8) + tid;
                int row = ci >> 3, cq = (ci & 7) ^ (row & 7);
                async16(Kg + row * HDim + cq * 8, &Ks[nb2][((it << 8) + (w4 << 6)) * 8]);
                async16(Vg + (size_t)row * Tseq + cq * 8, &VTs[nb2][((it << 8) + (w4 << 6)) * 8]);
            }
        }

        // S^T = K Q^T (rows = keys, cols = q)
        floatx4 st[4];
        #pragma unroll
        for (int sub = 0; sub < 4; ++sub) st[sub] = fz;
        #pragma unroll
        for (int ks = 0; ks < 2; ++ks) {
            bf16x8 kf[4];
            #pragma unroll
            for (int sub = 0; sub < 4; ++sub) {
                int krow = (sub << 4) + lm;
                int kc = ((ks << 2) + quad) ^ (krow & 7);
                kf[sub] = *(const bf16x8*)&Ks[cb][krow * 64 + kc * 8];
            }
            #pragma unroll
            for (int sub = 0; sub < 4; ++sub)
                st[sub] = __builtin_amdgcn_mfma_f32_16x16x32_bf16(
                    kf[sub], qf[ks], st[sub], 0, 0, 0);
        }

        // no-max softmax: P = exp2(s) (bf16), l += sum(P)
        const bool dm = (kt == jt);           // diagonal tile -> causal mask
        bf16x8 pf[2];                         // B-operand P frags (key halves)
        float rs = 0.f;
        #pragma unroll
        for (int cc = 0; cc < 2; ++cc)
            #pragma unroll
            for (int jj = 0; jj < 8; ++jj) {
                int sub = (cc << 1) + (jj >> 2), r = jj & 3;
                float val = st[sub][r];
                if (dm) {
                    int key = (kt << 6) + (sub << 4) + (quad << 2) + r;
                    if (key > qq) val = -3e38f;
                }
                float p = exp2f(val);
                rs += p;
                pf[cc][jj] = (bf16_t)p;
            }
        rs += __shfl_xor(rs, 16);
        rs += __shfl_xor(rs, 32);
        l_ += rs;

        // O^T += V^T P^T (sigma key-permutation baked into vt layout)
        #pragma unroll
        for (int cc = 0; cc < 2; ++cc) {
            bf16x8 vf[4];
            #pragma unroll
            for (int f = 0; f < 4; ++f) {
                int vrow = (f << 4) + lm;
                int vc = ((cc << 2) + quad) ^ (vrow & 7);
                vf[f] = *(const bf16x8*)&VTs[cb][vrow * 64 + vc * 8];
            }
            #pragma unroll
            for (int f = 0; f < 4; ++f)
                o_[f] = __builtin_amdgcn_mfma_f32_16x16x32_bf16(
                    vf[f], pf[cc], o_[f], 0, 0, 0);
        }
        __syncthreads();
    }

    // epilogue: O^T lane holds q=qq, d = f*16+quad*4+r
    {
        float inv = 1.f / l_;
        size_t base = ((size_t)(b * Tseq) + qq) * Cdim + (h << 6) + (quad << 2);
        #pragma unroll
        for (int f = 0; f < 4; ++f) {
            bf16x4 ov;
            #pragma unroll
            for (int r = 0; r < 4; ++r) ov[r] = (bf16_t)(o_[f][r] * inv);
            *(bf16x4*)&yb[base + (f << 4)] = ov;
        }
    }
}

// ---------------------------------------------------------------------------
// Proj GEMM, r13: tile 128x64 -> 512 blocks = 2 blocks/CU (was 128x128 ->
// 256 blocks = 1 block/CU = 1 wave/SIMD: the m97 loop's per-K-step vmcnt
// drain was fully exposed with no co-resident block to overlap it; this is
// the suspected ~40us hidden cost in the 185us total). Wave layout 2x2,
// wave-tile 64x32, acc[4][2], 12KB LDS. XCD remap: each XCD 4gm x 16gn,
// gn fastest (A-panel 1MB hot, B 2MB resident).
// ---------------------------------------------------------------------------
__global__ __launch_bounds__(256) void gemm_proj(
    const bf16_t* __restrict__ yb, const bf16_t* __restrict__ wpT,
    const float* __restrict__ bias, float* __restrict__ out)
{
    __shared__ bf16_t As[128 * 32];
    __shared__ bf16_t Bs[64 * 32];
    const int tid = threadIdx.x;
    const int lane = tid & 63, w = tid >> 6;
    const int lm = lane & 15, quad = lane >> 4;
    const int wy = w >> 1, wx = w & 1;
    const int bid = blockIdx.x;
    const int xcd = bid & 7, idx = bid >> 3;     // idx 0..63
    const int gm = (xcd << 2) + (idx >> 4);      // 0..31
    const int gn = idx & 15;                     // 0..15
    const int m0 = gm << 7, n0 = gn << 6;

    const floatx4 fz = {0.f, 0.f, 0.f, 0.f};
    floatx4 acc[4][2];
    #pragma unroll
    for (int i = 0; i < 4; i++)
        #pragma unroll
        for (int j = 0; j < 2; j++) acc[i][j] = fz;

    const bf16_t* Ag = yb + (size_t)m0 * Cdim;
    const bf16_t* Bg = wpT + (size_t)n0 * Cdim;

    for (int k0 = 0; k0 < Cdim; k0 += 32) {
        #pragma unroll
        for (int it = 0; it < 2; ++it) {         // A: 512 chunks
            int ci = (w << 7) + (it << 6) + lane;
            int row = ci >> 2, cq = (ci & 3) ^ (row & 3);
            async16(Ag + (size_t)row * Cdim + k0 + cq * 8, As + ((w << 7) + (it << 6)) * 8);
        }
        {                                        // B: 256 chunks (1/thread)
            int ci = tid;
            int row = ci >> 2, cq = (ci & 3) ^ (row & 3);
            async16(Bg + (size_t)row * Cdim + k0 + cq * 8, Bs + (w << 6) * 8);
        }
        __syncthreads();
        bf16x8 af[4], bfr[2];
        #pragma unroll
        for (int i = 0; i < 4; i++) {
            int row = (wy << 6) + (i << 4) + lm;
            int cq = quad ^ (lm & 3);
            af[i] = *(const bf16x8*)&As[row * 32 + cq * 8];
        }
        #pragma unroll
        for (int j = 0; j < 2; j++) {
            int row = (wx << 5) + (j << 4) + lm;
            int cq = quad ^ (lm & 3);
            bfr[j] = *(const bf16x8*)&Bs[row * 32 + cq * 8];
        }
        #pragma unroll
        for (int i = 0; i < 4; i++)
            #pragma unroll
            for (int j = 0; j < 2; j++)
                acc[i][j] = __builtin_amdgcn_mfma_f32_16x16x32_bf16(af[i], bfr[j], acc[i][j], 0, 0, 0);
        __syncthreads();
    }

    const int mb = m0 + (wy << 6);
    const int nb = n0 + (wx << 5);
    #pragma unroll
    for (int i = 0; i < 4; i++) {
        int mrow0 = mb + (i << 4) + (quad << 2);
        #pragma unroll
        for (int j = 0; j < 2; j++) {
            int n = nb + (j << 4) + lm;
            float bi = bias[n];
            #pragma unroll
            for (int r = 0; r < 4; r++)
                out[(size_t)(mrow0 + r) * Cdim + n] = acc[i][j][r] + bi;
        }
    }
}

extern "C" void kernel_launch(void* const* d_in, const int* in_sizes, int n_in,
                              void* d_out, int out_size, void* d_ws, size_t ws_size,
                              hipStream_t stream) {
    const float* x      = (const float*)d_in[0];
    const float* cosb   = (const float*)d_in[1];
    const float* sinb   = (const float*)d_in[2];
    const float* w_attn = (const float*)d_in[3];
    const float* b_attn = (const float*)d_in[4];
    const float* w_proj = (const float*)d_in[5];
    const float* b_proj = (const float*)d_in[6];

    char* ws = (char*)d_ws;
    bf16_t* xb  = (bf16_t*)(ws);                       //  8 MB: x bf16 (M,K)
    bf16_t* waT = (bf16_t*)(ws + (size_t)(8 << 20));   //  6 MB: w_attn^T (N,K)
    bf16_t* wpT = (bf16_t*)(ws + (size_t)(14 << 20));  //  2 MB: w_proj^T (N,K)
    bf16_t* qb  = (bf16_t*)(ws + (size_t)(16 << 20));  //  8 MB: q bf16 (BH,T,HD), pre-scaled
    bf16_t* kb  = (bf16_t*)(ws + (size_t)(24 << 20));  //  8 MB: k bf16 (BH,T,HD)
    bf16_t* vtb = (bf16_t*)(ws + (size_t)(32 << 20));  //  8 MB: v^T bf16 (BH,HD,T), key-permuted
    bf16_t* yb  = (bf16_t*)(ws + (size_t)(40 << 20));  //  8 MB: attn out (M,C)

    prep_kernel<<<6144, 256, 0, stream>>>(x, w_attn, w_proj, xb, waT, wpT);
    gemm_qkv<<<768, 256, 0, stream>>>(xb, waT, b_attn, cosb, sinb, qb, kb, vtb);
    attn_mfma<<<1024, 256, 0, stream>>>(qb, kb, vtb, yb);
    gemm_proj<<<512, 256, 0, stream>>>(yb, wpT, b_proj, (float*)d_out);
}

// Round 8
// 182.521 us; speedup vs baseline: 1.0497x; 1.0141x over previous
//
#include <hip/hip_runtime.h>
#include <hip/hip_bf16.h>
#include <math.h>

#define Bsz 2
#define Tseq 2048
#define Cdim 1024
#define Hn 16
#define HDim 64
#define Mrows 4096
#define N3 3072
#define QSCALE 0.1803368801111137f   /* 0.125 * log2(e) baked into Q */

typedef __bf16 bf16_t;
typedef __bf16 bf16x4 __attribute__((ext_vector_type(4)));
typedef __bf16 bf16x8 __attribute__((ext_vector_type(8)));
typedef float floatx4 __attribute__((ext_vector_type(4)));

__device__ __forceinline__ void async16(const void* g, void* l) {
    __builtin_amdgcn_global_load_lds(
        (const __attribute__((address_space(1))) void*)g,
        (__attribute__((address_space(3))) void*)l, 16, 0, 0);
}

// ---------------------------------------------------------------------------
// prep: fused fp32->bf16 convert of x + transpose-convert of w_attn, w_proj.
// blocks 0..2047: convert; 2048..5119: w_attn^T; 5120..6143: w_proj^T.
// ---------------------------------------------------------------------------
__global__ __launch_bounds__(256) void prep_kernel(
    const float* __restrict__ x, const float* __restrict__ w_attn,
    const float* __restrict__ w_proj, bf16_t* __restrict__ xb,
    bf16_t* __restrict__ waT, bf16_t* __restrict__ wpT)
{
    __shared__ float Ts[32][33];
    const int bid = blockIdx.x;
    if (bid < 2048) {
        size_t g = (size_t)bid * 256 + threadIdx.x;
        float4 a = *(const float4*)(x + g * 8);
        float4 b = *(const float4*)(x + g * 8 + 4);
        bf16x8 o;
        o[0] = (bf16_t)a.x; o[1] = (bf16_t)a.y; o[2] = (bf16_t)a.z; o[3] = (bf16_t)a.w;
        o[4] = (bf16_t)b.x; o[5] = (bf16_t)b.y; o[6] = (bf16_t)b.z; o[7] = (bf16_t)b.w;
        *(bf16x8*)(xb + g * 8) = o;
        return;
    }
    const float* in; bf16_t* out; int R, C, bx, by;
    if (bid < 5120) {
        int t = bid - 2048; in = w_attn; out = waT; R = Cdim; C = N3;
        bx = t % 96; by = t / 96;
    } else {
        int t = bid - 5120; in = w_proj; out = wpT; R = Cdim; C = Cdim;
        bx = t & 31; by = t >> 5;
    }
    int c0 = bx << 5, r0 = by << 5;
    int lr = threadIdx.x >> 3, lc = (threadIdx.x & 7) << 2;
    float4 v = *(const float4*)(in + (size_t)(r0 + lr) * C + c0 + lc);
    Ts[lr][lc] = v.x; Ts[lr][lc + 1] = v.y; Ts[lr][lc + 2] = v.z; Ts[lr][lc + 3] = v.w;
    __syncthreads();
    bf16x4 o;
    o[0] = (bf16_t)Ts[lc + 0][lr]; o[1] = (bf16_t)Ts[lc + 1][lr];
    o[2] = (bf16_t)Ts[lc + 2][lr]; o[3] = (bf16_t)Ts[lc + 3][lr];
    *(bf16x4*)(out + (size_t)(c0 + lr) * R + r0 + lc) = o;
}

// ---------------------------------------------------------------------------
// QKV GEMM, r14 = r5 body (measured best: 45-46us). Structure ceiling
// accepted after 5 failed variants; XCD remap keeps FETCH at 21.6MB.
// ---------------------------------------------------------------------------
__global__ __launch_bounds__(256) void gemm_qkv(
    const bf16_t* __restrict__ xb, const bf16_t* __restrict__ waT,
    const float* __restrict__ bias, const float* __restrict__ cosb,
    const float* __restrict__ sinb,
    bf16_t* __restrict__ qb, bf16_t* __restrict__ kb, bf16_t* __restrict__ vt)
{
    __shared__ bf16_t As[128 * 32];
    __shared__ bf16_t Bs[128 * 32];
    const int tid = threadIdx.x;
    const int lane = tid & 63, w = tid >> 6;
    const int lm = lane & 15, quad = lane >> 4;
    const int wy = w >> 1, wx = w & 1;
    const int bid = blockIdx.x;
    const int xcd = bid & 7, i5 = bid >> 3;
    const int gn = ((xcd & 1) * 12) + (i5 % 12);
    const int gm = ((xcd >> 1) * 8) + (i5 / 12);
    const int m0 = gm << 7, n0 = gn << 7;

    const floatx4 fz = {0.f, 0.f, 0.f, 0.f};
    floatx4 acc[4][4];
    #pragma unroll
    for (int i = 0; i < 4; i++)
        #pragma unroll
        for (int j = 0; j < 4; j++) acc[i][j] = fz;

    const bf16_t* Ag = xb + (size_t)m0 * Cdim;
    const bf16_t* Bg = waT + (size_t)n0 * Cdim;

    for (int k0 = 0; k0 < Cdim; k0 += 32) {
        #pragma unroll
        for (int it = 0; it < 2; ++it) {
            int ci = (w << 7) + (it << 6) + lane;
            int row = ci >> 2, cq = (ci & 3) ^ (row & 3);
            async16(Ag + (size_t)row * Cdim + k0 + cq * 8, As + ((w << 7) + (it << 6)) * 8);
            async16(Bg + (size_t)row * Cdim + k0 + cq * 8, Bs + ((w << 7) + (it << 6)) * 8);
        }
        __syncthreads();
        bf16x8 af[4], bfr[4];
        #pragma unroll
        for (int i = 0; i < 4; i++) {
            int row = (wy << 6) + (i << 4) + lm;
            int cq = quad ^ (lm & 3);
            af[i] = *(const bf16x8*)&As[row * 32 + cq * 8];
        }
        #pragma unroll
        for (int j = 0; j < 4; j++) {
            int row = (wx << 6) + (j << 4) + lm;
            int cq = quad ^ (lm & 3);
            bfr[j] = *(const bf16x8*)&Bs[row * 32 + cq * 8];
        }
        #pragma unroll
        for (int i = 0; i < 4; i++)
            #pragma unroll
            for (int j = 0; j < 4; j++)
                acc[i][j] = __builtin_amdgcn_mfma_f32_16x16x32_bf16(af[i], bfr[j], acc[i][j], 0, 0, 0);
        __syncthreads();
    }

    const int sec = n0 >> 10;                 // block-uniform: 0=q 1=k 2=v
    const int mb = m0 + (wy << 6);
    const int nb = n0 + (wx << 6);
    #pragma unroll
    for (int i = 0; i < 4; i++) {
        int mrow0 = mb + (i << 4) + (quad << 2);
        int b = mrow0 >> 11, t0 = mrow0 & 2047;
        #pragma unroll
        for (int j = 0; j < 4; j++) {
            int n = nb + (j << 4) + lm;
            float bi = bias[n];
            int rel = n & 1023;
            int h = rel >> 6, hd = rel & 63;
            if (sec == 2) {
                int tp = (t0 & ~31) | (((t0 >> 2) & 3) << 3) | (((t0 >> 4) & 1) << 2);
                bf16x4 pk;
                #pragma unroll
                for (int r = 0; r < 4; r++) pk[r] = (bf16_t)(acc[i][j][r] + bi);
                *(bf16x4*)&vt[((size_t)(b * Hn + h) * HDim + hd) * Tseq + tp] = pk;
            } else {
                bf16_t* dst = (sec == 0) ? qb : kb;
                const int ih = hd >> 1;
                const bool ev = !(hd & 1);
                #pragma unroll
                for (int r = 0; r < 4; r++) {
                    int t = t0 + r;
                    float v = acc[i][j][r] + bi;
                    float x = __shfl_xor(v, 1);        // rotary pair partner
                    float c = cosb[t * 32 + ih], s = sinb[t * 32 + ih];
                    float rv = ev ? (v * c - x * s) : (x * s + v * c);
                    if (sec == 0) rv *= QSCALE;
                    dst[((size_t)(b * Hn + h) * Tseq + t) * HDim + hd] = (bf16_t)rv;
                }
            }
        }
    }
}

// ---------------------------------------------------------------------------
// Flash attention, r14: counted-vmcnt pipeline (T3/T4 where we control the
// barrier). r0-vs-r1 data showed per-CU cost pinned at ~1470cyc/tile-iter
// independent of residency -> the per-iteration __syncthreads() vmcnt(0)
// drains (2 barriers + full drain of a prefetch issued ~1 phase earlier,
// x32 iterations) are the cost, not wave shortage.
// New schedule: 3 K/V buffers (48KB, 3 blocks/CU), prefetch distance 2,
// ONE raw s_barrier per iteration, vmcnt(4) (never 0 until the last iter):
//   iter kt: vmcnt(4)            // drains exactly tile-kt's 4 loads/thread
//            s_barrier           // all waves' tile-kt data visible (RAW ok:
//                                // vmcnt is per-wave; symmetric issue +
//                                // rendezvous covers cross-wave)
//            stage(kt+2)->buf[(kt+2)%3]   // WAR ok: that buf was last read
//                                // at compute(kt-1), done before barrier(kt)
//            compute(kt)
// Q-fragment loads drained by vmcnt(0) BEFORE staging so counts stay exact.
// sched_barrier(0) after the wait (rule #18). Tail: vmcnt(0) at kt==nk-1.
// Compute body unchanged: no-max softmax P=exp2(s), l=sum(P); PV = V^T P^T.
// ---------------------------------------------------------------------------
__global__ __launch_bounds__(256) void attn_mfma(
    const bf16_t* __restrict__ qb, const bf16_t* __restrict__ kb,
    const bf16_t* __restrict__ vt, bf16_t* __restrict__ yb)
{
    __shared__ bf16_t Ks[3][64 * 64];       // 24 KB
    __shared__ bf16_t VTs[3][64 * 64];      // 24 KB

    const int bid = blockIdx.x;
    const int jt = 31 - (bid >> 5);          // long blocks dispatch first
    const int bh = bid & 31;
    const int b = bh >> 4, h = bh & 15;
    const int tid = threadIdx.x;
    const int w4 = tid >> 6, lane = tid & 63, lm = lane & 15, quad = lane >> 4;
    const int nk = jt + 1;                   // kt = 0 .. jt (causal)

    const bf16_t* Kg0 = kb + (size_t)bh * Tseq * HDim;
    const bf16_t* Vg0 = vt + (size_t)bh * HDim * Tseq;

    // loop-invariant Q fragments (B-operand: n=lm, k); drain before staging
    const int qq = (jt << 6) + (w4 << 4) + lm;   // this lane's q row
    bf16x8 qf[2];
    {
        const bf16_t* Qg = qb + ((size_t)bh * Tseq + qq) * HDim;
        #pragma unroll
        for (int ks = 0; ks < 2; ++ks)
            qf[ks] = *(const bf16x8*)(Qg + (ks << 5) + (quad << 3));
    }
    asm volatile("s_waitcnt vmcnt(0)" ::: "memory");

    auto stagef = [&](int tile, int buf) {
        const bf16_t* Kg = Kg0 + (size_t)(tile << 6) * HDim;
        const bf16_t* Vg = Vg0 + (tile << 6);
        #pragma unroll
        for (int it = 0; it < 2; ++it) {
            int ci = (it << 8) + tid;
            int row = ci >> 3, cq = (ci & 7) ^ (row & 7);
            async16(Kg + row * HDim + cq * 8, &Ks[buf][((it << 8) + (w4 << 6)) * 8]);
            async16(Vg + (size_t)row * Tseq + cq * 8, &VTs[buf][((it << 8) + (w4 << 6)) * 8]);
        }
    };

    stagef(0, 0);                            // 4 loads/thread
    if (nk > 1) stagef(1, 1);                // 4 more

    const floatx4 fz = {0.f, 0.f, 0.f, 0.f};
    floatx4 o_[4];                           // O^T: [d-subtile]
    #pragma unroll
    for (int f = 0; f < 4; ++f) o_[f] = fz;
    float l_ = 0.f;

    int cb = 0, sb = 2;                      // cb=kt%3, sb=(kt+2)%3
    for (int kt = 0; kt < nk; ++kt) {
        if (kt == nk - 1) { asm volatile("s_waitcnt vmcnt(0)" ::: "memory"); }
        else             { asm volatile("s_waitcnt vmcnt(4)" ::: "memory"); }
        __builtin_amdgcn_s_barrier();
        __builtin_amdgcn_sched_barrier(0);
        if (kt + 2 < nk) stagef(kt + 2, sb);

        // S^T = K Q^T (rows = keys, cols = q)
        floatx4 st[4];
        #pragma unroll
        for (int sub = 0; sub < 4; ++sub) st[sub] = fz;
        #pragma unroll
        for (int ks = 0; ks < 2; ++ks) {
            bf16x8 kf[4];
            #pragma unroll
            for (int sub = 0; sub < 4; ++sub) {
                int krow = (sub << 4) + lm;
                int kc = ((ks << 2) + quad) ^ (krow & 7);
                kf[sub] = *(const bf16x8*)&Ks[cb][krow * 64 + kc * 8];
            }
            #pragma unroll
            for (int sub = 0; sub < 4; ++sub)
                st[sub] = __builtin_amdgcn_mfma_f32_16x16x32_bf16(
                    kf[sub], qf[ks], st[sub], 0, 0, 0);
        }

        // no-max softmax: P = exp2(s) (bf16), l += sum(P)
        const bool dm = (kt == jt);           // diagonal tile -> causal mask
        bf16x8 pf[2];                         // B-operand P frags (key halves)
        float rs = 0.f;
        #pragma unroll
        for (int cc = 0; cc < 2; ++cc)
            #pragma unroll
            for (int jj = 0; jj < 8; ++jj) {
                int sub = (cc << 1) + (jj >> 2), r = jj & 3;
                float val = st[sub][r];
                if (dm) {
                    int key = (kt << 6) + (sub << 4) + (quad << 2) + r;
                    if (key > qq) val = -3e38f;
                }
                float p = exp2f(val);
                rs += p;
                pf[cc][jj] = (bf16_t)p;
            }
        rs += __shfl_xor(rs, 16);
        rs += __shfl_xor(rs, 32);
        l_ += rs;

        // O^T += V^T P^T (sigma key-permutation baked into vt layout)
        #pragma unroll
        for (int cc = 0; cc < 2; ++cc) {
            bf16x8 vf[4];
            #pragma unroll
            for (int f = 0; f < 4; ++f) {
                int vrow = (f << 4) + lm;
                int vc = ((cc << 2) + quad) ^ (vrow & 7);
                vf[f] = *(const bf16x8*)&VTs[cb][vrow * 64 + vc * 8];
            }
            #pragma unroll
            for (int f = 0; f < 4; ++f)
                o_[f] = __builtin_amdgcn_mfma_f32_16x16x32_bf16(
                    vf[f], pf[cc], o_[f], 0, 0, 0);
        }
        sb = cb; cb = (cb == 2) ? 0 : cb + 1;
    }

    // epilogue: O^T lane holds q=qq, d = f*16+quad*4+r
    {
        float inv = 1.f / l_;
        size_t base = ((size_t)(b * Tseq) + qq) * Cdim + (h << 6) + (quad << 2);
        #pragma unroll
        for (int f = 0; f < 4; ++f) {
            bf16x4 ov;
            #pragma unroll
            for (int r = 0; r < 4; ++r) ov[r] = (bf16_t)(o_[f][r] * inv);
            *(bf16x4*)&yb[base + (f << 4)] = ov;
        }
    }
}

// ---------------------------------------------------------------------------
// Proj GEMM, r13 form (128x64 tile, 512 blocks, 2/CU — measured neutral vs
// 128x128; kept for the lower LDS footprint).
// ---------------------------------------------------------------------------
__global__ __launch_bounds__(256) void gemm_proj(
    const bf16_t* __restrict__ yb, const bf16_t* __restrict__ wpT,
    const float* __restrict__ bias, float* __restrict__ out)
{
    __shared__ bf16_t As[128 * 32];
    __shared__ bf16_t Bs[64 * 32];
    const int tid = threadIdx.x;
    const int lane = tid & 63, w = tid >> 6;
    const int lm = lane & 15, quad = lane >> 4;
    const int wy = w >> 1, wx = w & 1;
    const int bid = blockIdx.x;
    const int xcd = bid & 7, idx = bid >> 3;     // idx 0..63
    const int gm = (xcd << 2) + (idx >> 4);      // 0..31
    const int gn = idx & 15;                     // 0..15
    const int m0 = gm << 7, n0 = gn << 6;

    const floatx4 fz = {0.f, 0.f, 0.f, 0.f};
    floatx4 acc[4][2];
    #pragma unroll
    for (int i = 0; i < 4; i++)
        #pragma unroll
        for (int j = 0; j < 2; j++) acc[i][j] = fz;

    const bf16_t* Ag = yb + (size_t)m0 * Cdim;
    const bf16_t* Bg = wpT + (size_t)n0 * Cdim;

    for (int k0 = 0; k0 < Cdim; k0 += 32) {
        #pragma unroll
        for (int it = 0; it < 2; ++it) {         // A: 512 chunks
            int ci = (w << 7) + (it << 6) + lane;
            int row = ci >> 2, cq = (ci & 3) ^ (row & 3);
            async16(Ag + (size_t)row * Cdim + k0 + cq * 8, As + ((w << 7) + (it << 6)) * 8);
        }
        {                                        // B: 256 chunks (1/thread)
            int ci = tid;
            int row = ci >> 2, cq = (ci & 3) ^ (row & 3);
            async16(Bg + (size_t)row * Cdim + k0 + cq * 8, Bs + (w << 6) * 8);
        }
        __syncthreads();
        bf16x8 af[4], bfr[2];
        #pragma unroll
        for (int i = 0; i < 4; i++) {
            int row = (wy << 6) + (i << 4) + lm;
            int cq = quad ^ (lm & 3);
            af[i] = *(const bf16x8*)&As[row * 32 + cq * 8];
        }
        #pragma unroll
        for (int j = 0; j < 2; j++) {
            int row = (wx << 5) + (j << 4) + lm;
            int cq = quad ^ (lm & 3);
            bfr[j] = *(const bf16x8*)&Bs[row * 32 + cq * 8];
        }
        #pragma unroll
        for (int i = 0; i < 4; i++)
            #pragma unroll
            for (int j = 0; j < 2; j++)
                acc[i][j] = __builtin_amdgcn_mfma_f32_16x16x32_bf16(af[i], bfr[j], acc[i][j], 0, 0, 0);
        __syncthreads();
    }

    const int mb = m0 + (wy << 6);
    const int nb = n0 + (wx << 5);
    #pragma unroll
    for (int i = 0; i < 4; i++) {
        int mrow0 = mb + (i << 4) + (quad << 2);
        #pragma unroll
        for (int j = 0; j < 2; j++) {
            int n = nb + (j << 4) + lm;
            float bi = bias[n];
            #pragma unroll
            for (int r = 0; r < 4; r++)
                out[(size_t)(mrow0 + r) * Cdim + n] = acc[i][j][r] + bi;
        }
    }
}

extern "C" void kernel_launch(void* const* d_in, const int* in_sizes, int n_in,
                              void* d_out, int out_size, void* d_ws, size_t ws_size,
                              hipStream_t stream) {
    const float* x      = (const float*)d_in[0];
    const float* cosb   = (const float*)d_in[1];
    const float* sinb   = (const float*)d_in[2];
    const float* w_attn = (const float*)d_in[3];
    const float* b_attn = (const float*)d_in[4];
    const float* w_proj = (const float*)d_in[5];
    const float* b_proj = (const float*)d_in[6];

    char* ws = (char*)d_ws;
    bf16_t* xb  = (bf16_t*)(ws);                       //  8 MB: x bf16 (M,K)
    bf16_t* waT = (bf16_t*)(ws + (size_t)(8 << 20));   //  6 MB: w_attn^T (N,K)
    bf16_t* wpT = (bf16_t*)(ws + (size_t)(14 << 20));  //  2 MB: w_proj^T (N,K)
    bf16_t* qb  = (bf16_t*)(ws + (size_t)(16 << 20));  //  8 MB: q bf16 (BH,T,HD), pre-scaled
    bf16_t* kb  = (bf16_t*)(ws + (size_t)(24 << 20));  //  8 MB: k bf16 (BH,T,HD)
    bf16_t* vtb = (bf16_t*)(ws + (size_t)(32 << 20));  //  8 MB: v^T bf16 (BH,HD,T), key-permuted
    bf16_t* yb  = (bf16_t*)(ws + (size_t)(40 << 20));  //  8 MB: attn out (M,C)

    prep_kernel<<<6144, 256, 0, stream>>>(x, w_attn, w_proj, xb, waT, wpT);
    gemm_qkv<<<768, 256, 0, stream>>>(xb, waT, b_attn, cosb, sinb, qb, kb, vtb);
    attn_mfma<<<1024, 256, 0, stream>>>(qb, kb, vtb, yb);
    gemm_proj<<<512, 256, 0, stream>>>(yb, wpT, b_proj, (float*)d_out);
}